// Round 1
// baseline (3391.698 us; speedup 1.0000x reference)
//
#include <hip/hip_runtime.h>

#define NP 100000
#define NA 50000
#define NE 500000
#define HID 128

// ---------------- workspace layout (bytes) ----------------
// bufA:  float[100000*128]  @ 0          (51,200,000 B)  -- scatter sum accumulator
// cntA:  int[100000]        @ 51,200,000 (400,000 B)
// W region @ 51,600,384 (512-aligned):
//   ApT,BpT,CpT,AaT,BaT each 128*128*4 = 65536 B (stored TRANSPOSED: MT[k*128+j] = M[j][k])
//   then bp0,bpc,bpw,ba0,bab each 128*4 = 512 B
#define OFF_CNT  51200000ull
#define OFF_W    51600384ull
#define OFF_B    (OFF_W + 5ull*65536ull)

// ---------------- weight fusion ----------------
// grid 640 blocks x 128 threads; block = (matrix m, out-row r); thread = in-col c
__global__ void fuse_w(const float* __restrict__ Wc_p, const float* __restrict__ Ws_p,
                       const float* __restrict__ W_cites, const float* __restrict__ W_writes,
                       const float* __restrict__ Wc_a, const float* __restrict__ Ws_a,
                       const float* __restrict__ W_written, float* __restrict__ wsW) {
    int m = blockIdx.x >> 7;
    int r = blockIdx.x & 127;
    int c = threadIdx.x;
    const float* L; const float* R; float scale = 1.f;
    switch (m) {
        case 0:  L = Wc_p + r*256;       R = Ws_p;      break;            // Ap = Wc1_p @ Ws_p
        case 1:  L = Wc_p + r*256 + 128; R = W_cites;   scale = 0.5f; break; // Bp = .5*Wc2_p @ W_cites
        case 2:  L = Wc_p + r*256 + 128; R = W_writes;  scale = 0.5f; break; // Cp
        case 3:  L = Wc_a + r*256;       R = Ws_a;      break;            // Aa
        default: L = Wc_a + r*256 + 128; R = W_written; break;            // Ba
    }
    float acc = 0.f;
    for (int k = 0; k < 128; ++k) acc += L[k] * R[k*128 + c];
    // transposed store: MT[c][r]
    wsW[m*16384 + c*128 + r] = scale * acc;
}

// 640 threads total: (vector m, element j)
__global__ void fuse_b(const float* __restrict__ Wc_p, const float* __restrict__ bs_p,
                       const float* __restrict__ bc_p, const float* __restrict__ b_cites,
                       const float* __restrict__ b_writes,
                       const float* __restrict__ Wc_a, const float* __restrict__ bs_a,
                       const float* __restrict__ bc_a, const float* __restrict__ b_written,
                       float* __restrict__ wsB) {
    int t = blockIdx.x * blockDim.x + threadIdx.x;
    if (t >= 640) return;
    int m = t >> 7, j = t & 127;
    float acc = 0.f;
    switch (m) {
        case 0:  for (int k = 0; k < 128; ++k) acc += Wc_p[j*256+k]     * bs_p[k];     acc += bc_p[j]; break;
        case 1:  for (int k = 0; k < 128; ++k) acc += Wc_p[j*256+128+k] * b_cites[k];  acc *= 0.5f;    break;
        case 2:  for (int k = 0; k < 128; ++k) acc += Wc_p[j*256+128+k] * b_writes[k]; acc *= 0.5f;    break;
        case 3:  for (int k = 0; k < 128; ++k) acc += Wc_a[j*256+k]     * bs_a[k];     acc += bc_a[j]; break;
        default: for (int k = 0; k < 128; ++k) acc += Wc_a[j*256+128+k] * b_written[k];                break;
    }
    wsB[m*128 + j] = acc;
}

// ---------------- scatter-sum of raw features ----------------
// 32 threads per edge, float4 each; atomic f32 adds into sum[dst]
__global__ void scatter_sum(const float* __restrict__ x, const int* __restrict__ ei,
                            float* __restrict__ sum, int* __restrict__ cnt) {
    long long gid = (long long)blockIdx.x * blockDim.x + threadIdx.x;
    int e = (int)(gid >> 5);
    int l = (int)(gid & 31);
    if (e >= NE) return;
    int src = ei[e];
    int dst = ei[NE + e];
    float4 v = ((const float4*)x)[(long long)src*32 + l];
    float* s = sum + (long long)dst*128 + l*4;
    atomicAdd(s+0, v.x); atomicAdd(s+1, v.y);
    atomicAdd(s+2, v.z); atomicAdd(s+3, v.w);
    if (l == 0) atomicAdd(cnt + dst, 1);
}

// ---------------- fused linear pass: out[i] (+)= M @ v_i (+bias) ----------------
// MT is pre-transposed [k][j]. v from global (rows broadcast within wave).
// MEAN: v_i = src_i / max(cnt_i,1); bias (BMASK) gated by cnt_i>0.
// block: 256 threads, 64 rows; thread: 8 rows x 4 cols.
template<bool MEAN, bool ACC, bool RELU, bool BVEC, bool BMASK>
__global__ __launch_bounds__(256) void lin_pass(
        const float* __restrict__ src, const int* __restrict__ cnt,
        const float* __restrict__ MT, const float* __restrict__ bias,
        float* __restrict__ out, int nRows) {
    __shared__ float wT[128*128];  // 64 KB
    int tid = threadIdx.x;
    for (int i = tid; i < 128*32; i += 256)
        ((float4*)wT)[i] = ((const float4*)MT)[i];
    __syncthreads();

    int colg = tid & 31;        // 32 col-groups * 4 cols
    int rowg = tid >> 5;        // 8 row-groups * 8 rows
    int row0 = blockIdx.x * 64 + rowg * 8;

    float scale[8], mask[8];
#pragma unroll
    for (int r = 0; r < 8; ++r) {
        int gr = row0 + r;
        if (MEAN) {
            int c = (gr < nRows) ? cnt[gr] : 0;
            scale[r] = 1.f / (float)max(c, 1);
            mask[r]  = (c > 0) ? 1.f : 0.f;
        } else { scale[r] = 1.f; mask[r] = 1.f; }
    }

    float acc[8][4] = {};
    for (int k4 = 0; k4 < 32; ++k4) {
        float4 w0 = ((float4*)wT)[(k4*4+0)*32 + colg];
        float4 w1 = ((float4*)wT)[(k4*4+1)*32 + colg];
        float4 w2 = ((float4*)wT)[(k4*4+2)*32 + colg];
        float4 w3 = ((float4*)wT)[(k4*4+3)*32 + colg];
#pragma unroll
        for (int r = 0; r < 8; ++r) {
            int gr = row0 + r;
            float4 v = (gr < nRows) ? ((const float4*)src)[(long long)gr*32 + k4]
                                    : make_float4(0.f,0.f,0.f,0.f);
            acc[r][0] += v.x*w0.x; acc[r][1] += v.x*w0.y; acc[r][2] += v.x*w0.z; acc[r][3] += v.x*w0.w;
            acc[r][0] += v.y*w1.x; acc[r][1] += v.y*w1.y; acc[r][2] += v.y*w1.z; acc[r][3] += v.y*w1.w;
            acc[r][0] += v.z*w2.x; acc[r][1] += v.z*w2.y; acc[r][2] += v.z*w2.z; acc[r][3] += v.z*w2.w;
            acc[r][0] += v.w*w3.x; acc[r][1] += v.w*w3.y; acc[r][2] += v.w*w3.z; acc[r][3] += v.w*w3.w;
        }
    }

    float4 b4 = make_float4(0.f,0.f,0.f,0.f);
    if (BVEC || BMASK) b4 = ((const float4*)bias)[colg];

#pragma unroll
    for (int r = 0; r < 8; ++r) {
        int gr = row0 + r;
        if (gr >= nRows) continue;
        float s = MEAN ? scale[r] : 1.f;
        float4 o;
        o.x = acc[r][0]*s; o.y = acc[r][1]*s; o.z = acc[r][2]*s; o.w = acc[r][3]*s;
        if (BVEC)  { o.x += b4.x; o.y += b4.y; o.z += b4.z; o.w += b4.w; }
        if (BMASK) { float mk = mask[r];
                     o.x += mk*b4.x; o.y += mk*b4.y; o.z += mk*b4.z; o.w += mk*b4.w; }
        long long o4 = (long long)gr*32 + colg;
        if (ACC) { float4 p = ((float4*)out)[o4];
                   o.x += p.x; o.y += p.y; o.z += p.z; o.w += p.w; }
        if (RELU) { o.x = fmaxf(o.x,0.f); o.y = fmaxf(o.y,0.f);
                    o.z = fmaxf(o.z,0.f); o.w = fmaxf(o.w,0.f); }
        ((float4*)out)[o4] = o;
    }
}

extern "C" void kernel_launch(void* const* d_in, const int* in_sizes, int n_in,
                              void* d_out, int out_size, void* d_ws, size_t ws_size,
                              hipStream_t stream) {
    const float* x_paper   = (const float*)d_in[0];
    const float* x_author  = (const float*)d_in[1];
    const int*   ei_cites  = (const int*)d_in[2];
    const int*   ei_writes = (const int*)d_in[3];
    const int*   ei_written= (const int*)d_in[4];
    const float* W_cites   = (const float*)d_in[5];
    const float* b_cites   = (const float*)d_in[6];
    const float* W_writes  = (const float*)d_in[7];
    const float* b_writes  = (const float*)d_in[8];
    const float* W_written = (const float*)d_in[9];
    const float* b_written = (const float*)d_in[10];
    const float* Ws_paper  = (const float*)d_in[11];
    const float* bs_paper  = (const float*)d_in[12];
    const float* Ws_author = (const float*)d_in[13];
    const float* bs_author = (const float*)d_in[14];
    const float* Wc_paper  = (const float*)d_in[15];
    const float* bc_paper  = (const float*)d_in[16];
    const float* Wc_author = (const float*)d_in[17];
    const float* bc_author = (const float*)d_in[18];

    char* ws = (char*)d_ws;
    float* bufA = (float*)ws;
    int*   cntA = (int*)(ws + OFF_CNT);
    float* wsW  = (float*)(ws + OFF_W);
    float* wsB  = (float*)(ws + OFF_B);
    const float* ApT = wsW;
    const float* BpT = wsW + 16384;
    const float* CpT = wsW + 2*16384;
    const float* AaT = wsW + 3*16384;
    const float* BaT = wsW + 4*16384;
    const float* bp0 = wsB;
    const float* bpc = wsB + 128;
    const float* bpw = wsB + 2*128;
    const float* ba0 = wsB + 3*128;
    const float* bab = wsB + 4*128;

    float* out_p = (float*)d_out;
    float* out_a = out_p + (long long)NP*HID;

    // fused weights/biases
    fuse_w<<<640, 128, 0, stream>>>(Wc_paper, Ws_paper, W_cites, W_writes,
                                    Wc_author, Ws_author, W_written, wsW);
    fuse_b<<<3, 256, 0, stream>>>(Wc_paper, bs_paper, bc_paper, b_cites, b_writes,
                                  Wc_author, bs_author, bc_author, b_written, wsB);

    const int scatterBlocks = (NE*32 + 255) / 256;   // 62500
    const int gP = (NP + 63) / 64;                   // 1563
    const int gA = (NA + 63) / 64;                   // 782

    // ---- cites (paper -> paper) ----
    hipMemsetAsync(d_ws, 0, OFF_CNT + 400000ull, stream);
    scatter_sum<<<scatterBlocks, 256, 0, stream>>>(x_paper, ei_cites, bufA, cntA);
    // out_p = Ap@x_p + bp0
    lin_pass<false,false,false,true,false><<<gP, 256, 0, stream>>>(
        x_paper, nullptr, ApT, bp0, out_p, NP);
    // out_p += Bp@mean_cites + mask*bpc
    lin_pass<true,true,false,false,true><<<gP, 256, 0, stream>>>(
        bufA, cntA, BpT, bpc, out_p, NP);

    // ---- writes (author -> paper) ----
    hipMemsetAsync(d_ws, 0, OFF_CNT + 400000ull, stream);
    scatter_sum<<<scatterBlocks, 256, 0, stream>>>(x_author, ei_writes, bufA, cntA);
    // out_p += Cp@mean_writes + mask*bpw ; relu
    lin_pass<true,true,true,false,true><<<gP, 256, 0, stream>>>(
        bufA, cntA, CpT, bpw, out_p, NP);

    // ---- written (paper -> author) ----
    hipMemsetAsync(d_ws, 0, OFF_CNT + 400000ull, stream);
    scatter_sum<<<scatterBlocks, 256, 0, stream>>>(x_paper, ei_written, bufA, cntA);
    // out_a = Aa@x_a + ba0
    lin_pass<false,false,false,true,false><<<gA, 256, 0, stream>>>(
        x_author, nullptr, AaT, ba0, out_a, NA);
    // out_a += Ba@mean_written + mask*bab ; relu
    lin_pass<true,true,true,false,true><<<gA, 256, 0, stream>>>(
        bufA, cntA, BaT, bab, out_a, NA);
}

// Round 2
// 1078.049 us; speedup vs baseline: 3.1461x; 3.1461x over previous
//
#include <hip/hip_runtime.h>

#define NP 100000
#define NA 50000
#define NE 500000
#define HID 128

// ---------------- workspace layout (bytes) ----------------
// bufA:     float[100000*128] @ 0           (51,200,000)
// cntA:     int[100000]       @ 51,200,000  (400,000)
// rowStart: int[100000]       @ 51,600,000  (400,000)
// cursor:   int[100000]       @ 52,000,000  (400,000)
// srcIdx:   int[500000]       @ 52,400,000  (2,000,000)
// bsum:     int[128]          @ 54,400,000  (512)
// wsW: 5 x 65536              @ 54,400,512
// wsB: 5 x 512                @ 54,728,192
#define OFF_CNT  51200000ull
#define OFF_ROW  51600000ull
#define OFF_CUR  52000000ull
#define OFF_SRC  52400000ull
#define OFF_BSUM 54400000ull
#define OFF_W    54400512ull
#define OFF_B    54728192ull

// ---------------- weight fusion ----------------
__global__ void fuse_w(const float* __restrict__ Wc_p, const float* __restrict__ Ws_p,
                       const float* __restrict__ W_cites, const float* __restrict__ W_writes,
                       const float* __restrict__ Wc_a, const float* __restrict__ Ws_a,
                       const float* __restrict__ W_written, float* __restrict__ wsW) {
    int m = blockIdx.x >> 7;
    int r = blockIdx.x & 127;
    int c = threadIdx.x;
    const float* L; const float* R; float scale = 1.f;
    switch (m) {
        case 0:  L = Wc_p + r*256;       R = Ws_p;      break;
        case 1:  L = Wc_p + r*256 + 128; R = W_cites;   scale = 0.5f; break;
        case 2:  L = Wc_p + r*256 + 128; R = W_writes;  scale = 0.5f; break;
        case 3:  L = Wc_a + r*256;       R = Ws_a;      break;
        default: L = Wc_a + r*256 + 128; R = W_written; break;
    }
    float acc = 0.f;
    for (int k = 0; k < 128; ++k) acc += L[k] * R[k*128 + c];
    wsW[m*16384 + c*128 + r] = scale * acc;   // store transposed
}

__global__ void fuse_b(const float* __restrict__ Wc_p, const float* __restrict__ bs_p,
                       const float* __restrict__ bc_p, const float* __restrict__ b_cites,
                       const float* __restrict__ b_writes,
                       const float* __restrict__ Wc_a, const float* __restrict__ bs_a,
                       const float* __restrict__ bc_a, const float* __restrict__ b_written,
                       float* __restrict__ wsB) {
    int t = blockIdx.x * blockDim.x + threadIdx.x;
    if (t >= 640) return;
    int m = t >> 7, j = t & 127;
    float acc = 0.f;
    switch (m) {
        case 0:  for (int k = 0; k < 128; ++k) acc += Wc_p[j*256+k]     * bs_p[k];     acc += bc_p[j]; break;
        case 1:  for (int k = 0; k < 128; ++k) acc += Wc_p[j*256+128+k] * b_cites[k];  acc *= 0.5f;    break;
        case 2:  for (int k = 0; k < 128; ++k) acc += Wc_p[j*256+128+k] * b_writes[k]; acc *= 0.5f;    break;
        case 3:  for (int k = 0; k < 128; ++k) acc += Wc_a[j*256+k]     * bs_a[k];     acc += bc_a[j]; break;
        default: for (int k = 0; k < 128; ++k) acc += Wc_a[j*256+128+k] * b_written[k];                break;
    }
    wsB[m*128 + j] = acc;
}

// ---------------- CSR build ----------------
__global__ void hist_dst(const int* __restrict__ ei, int* __restrict__ cnt) {
    int e = blockIdx.x * blockDim.x + threadIdx.x;
    if (e < NE) atomicAdd(cnt + ei[NE + e], 1);
}

// per-chunk (1024 elems) sums
__global__ void scan_sums(const int* __restrict__ cnt, int* __restrict__ bsum, int n) {
    __shared__ int s[256];
    int base = blockIdx.x * 1024;
    int t = threadIdx.x;
    int v = 0;
#pragma unroll
    for (int j = 0; j < 4; ++j) { int i = base + t*4 + j; if (i < n) v += cnt[i]; }
    s[t] = v; __syncthreads();
    for (int off = 128; off > 0; off >>= 1) { if (t < off) s[t] += s[t+off]; __syncthreads(); }
    if (t == 0) bsum[blockIdx.x] = s[0];
}

// exclusive scan of chunk sums (nb <= 128), single block
__global__ void scan_tops(int* __restrict__ bsum, int nb) {
    __shared__ int s[128];
    int t = threadIdx.x;
    if (t < nb) s[t] = bsum[t];
    __syncthreads();
    if (t == 0) { int acc = 0; for (int i = 0; i < nb; ++i) { int v = s[i]; s[i] = acc; acc += v; } }
    __syncthreads();
    if (t < nb) bsum[t] = s[t];
}

// per-chunk exclusive scan + chunk offset -> rowStart, cursor
__global__ void scan_chunks(const int* __restrict__ cnt, const int* __restrict__ bsum,
                            int* __restrict__ rowStart, int* __restrict__ cursor, int n) {
    __shared__ int s[256];
    int base = blockIdx.x * 1024;
    int t = threadIdx.x;
    int loc[4]; int v = 0;
#pragma unroll
    for (int j = 0; j < 4; ++j) { int i = base + t*4 + j; loc[j] = (i < n) ? cnt[i] : 0; v += loc[j]; }
    s[t] = v; __syncthreads();
    for (int off = 1; off < 256; off <<= 1) {
        int tmp = (t >= off) ? s[t - off] : 0;
        __syncthreads();
        s[t] += tmp;
        __syncthreads();
    }
    int excl = s[t] - v + bsum[blockIdx.x];
#pragma unroll
    for (int j = 0; j < 4; ++j) {
        int i = base + t*4 + j;
        if (i < n) { rowStart[i] = excl; cursor[i] = excl; excl += loc[j]; }
    }
}

__global__ void csr_fill(const int* __restrict__ ei, int* __restrict__ cursor,
                         int* __restrict__ srcIdx) {
    int e = blockIdx.x * blockDim.x + threadIdx.x;
    if (e < NE) {
        int d = ei[NE + e];
        int p = atomicAdd(cursor + d, 1);
        srcIdx[p] = ei[e];
    }
}

// ---------------- gather-aggregate: one wave per dst node ----------------
__global__ __launch_bounds__(256) void csr_aggregate(
        const float* __restrict__ x, const int* __restrict__ srcIdx,
        const int* __restrict__ rowStart, const int* __restrict__ cnt,
        float* __restrict__ sum, int nDst) {
    int wid = (int)((blockIdx.x * 256 + threadIdx.x) >> 6);
    int lane = threadIdx.x & 63;
    if (wid >= nDst) return;
    int beg = rowStart[wid];
    int n = cnt[wid];
    float2 a0 = make_float2(0.f, 0.f), a1 = make_float2(0.f, 0.f);
    int j = 0;
    for (; j + 2 <= n; j += 2) {
        int s0 = srcIdx[beg + j];
        int s1 = srcIdx[beg + j + 1];
        float2 v0 = ((const float2*)x)[(long long)s0 * 64 + lane];
        float2 v1 = ((const float2*)x)[(long long)s1 * 64 + lane];
        a0.x += v0.x; a0.y += v0.y;
        a1.x += v1.x; a1.y += v1.y;
    }
    if (j < n) {
        int s0 = srcIdx[beg + j];
        float2 v0 = ((const float2*)x)[(long long)s0 * 64 + lane];
        a0.x += v0.x; a0.y += v0.y;
    }
    a0.x += a1.x; a0.y += a1.y;
    ((float2*)sum)[(long long)wid * 64 + lane] = a0;
}

// ---------------- fused linear pass (unchanged) ----------------
template<bool MEAN, bool ACC, bool RELU, bool BVEC, bool BMASK>
__global__ __launch_bounds__(256) void lin_pass(
        const float* __restrict__ src, const int* __restrict__ cnt,
        const float* __restrict__ MT, const float* __restrict__ bias,
        float* __restrict__ out, int nRows) {
    __shared__ float wT[128*128];
    int tid = threadIdx.x;
    for (int i = tid; i < 128*32; i += 256)
        ((float4*)wT)[i] = ((const float4*)MT)[i];
    __syncthreads();

    int colg = tid & 31;
    int rowg = tid >> 5;
    int row0 = blockIdx.x * 64 + rowg * 8;

    float scale[8], mask[8];
#pragma unroll
    for (int r = 0; r < 8; ++r) {
        int gr = row0 + r;
        if (MEAN) {
            int c = (gr < nRows) ? cnt[gr] : 0;
            scale[r] = 1.f / (float)max(c, 1);
            mask[r]  = (c > 0) ? 1.f : 0.f;
        } else { scale[r] = 1.f; mask[r] = 1.f; }
    }

    float acc[8][4] = {};
    for (int k4 = 0; k4 < 32; ++k4) {
        float4 w0 = ((float4*)wT)[(k4*4+0)*32 + colg];
        float4 w1 = ((float4*)wT)[(k4*4+1)*32 + colg];
        float4 w2 = ((float4*)wT)[(k4*4+2)*32 + colg];
        float4 w3 = ((float4*)wT)[(k4*4+3)*32 + colg];
#pragma unroll
        for (int r = 0; r < 8; ++r) {
            int gr = row0 + r;
            float4 v = (gr < nRows) ? ((const float4*)src)[(long long)gr*32 + k4]
                                    : make_float4(0.f,0.f,0.f,0.f);
            acc[r][0] += v.x*w0.x; acc[r][1] += v.x*w0.y; acc[r][2] += v.x*w0.z; acc[r][3] += v.x*w0.w;
            acc[r][0] += v.y*w1.x; acc[r][1] += v.y*w1.y; acc[r][2] += v.y*w1.z; acc[r][3] += v.y*w1.w;
            acc[r][0] += v.z*w2.x; acc[r][1] += v.z*w2.y; acc[r][2] += v.z*w2.z; acc[r][3] += v.z*w2.w;
            acc[r][0] += v.w*w3.x; acc[r][1] += v.w*w3.y; acc[r][2] += v.w*w3.z; acc[r][3] += v.w*w3.w;
        }
    }

    float4 b4 = make_float4(0.f,0.f,0.f,0.f);
    if (BVEC || BMASK) b4 = ((const float4*)bias)[colg];

#pragma unroll
    for (int r = 0; r < 8; ++r) {
        int gr = row0 + r;
        if (gr >= nRows) continue;
        float s = MEAN ? scale[r] : 1.f;
        float4 o;
        o.x = acc[r][0]*s; o.y = acc[r][1]*s; o.z = acc[r][2]*s; o.w = acc[r][3]*s;
        if (BVEC)  { o.x += b4.x; o.y += b4.y; o.z += b4.z; o.w += b4.w; }
        if (BMASK) { float mk = mask[r];
                     o.x += mk*b4.x; o.y += mk*b4.y; o.z += mk*b4.z; o.w += mk*b4.w; }
        long long o4 = (long long)gr*32 + colg;
        if (ACC) { float4 p = ((float4*)out)[o4];
                   o.x += p.x; o.y += p.y; o.z += p.z; o.w += p.w; }
        if (RELU) { o.x = fmaxf(o.x,0.f); o.y = fmaxf(o.y,0.f);
                    o.z = fmaxf(o.z,0.f); o.w = fmaxf(o.w,0.f); }
        ((float4*)out)[o4] = o;
    }
}

static inline void build_csr_and_aggregate(const float* x, const int* ei, int nDst,
                                           char* ws, hipStream_t stream) {
    int*   cnt      = (int*)(ws + OFF_CNT);
    int*   rowStart = (int*)(ws + OFF_ROW);
    int*   cursor   = (int*)(ws + OFF_CUR);
    int*   srcIdx   = (int*)(ws + OFF_SRC);
    int*   bsum     = (int*)(ws + OFF_BSUM);
    float* bufA     = (float*)ws;

    const int edgeBlocks = (NE + 255) / 256;
    const int nChunks = (nDst + 1023) / 1024;

    hipMemsetAsync(cnt, 0, (size_t)nDst * 4, stream);
    hist_dst<<<edgeBlocks, 256, 0, stream>>>(ei, cnt);
    scan_sums<<<nChunks, 256, 0, stream>>>(cnt, bsum, nDst);
    scan_tops<<<1, 128, 0, stream>>>(bsum, nChunks);
    scan_chunks<<<nChunks, 256, 0, stream>>>(cnt, bsum, rowStart, cursor, nDst);
    csr_fill<<<edgeBlocks, 256, 0, stream>>>(ei, cursor, srcIdx);
    csr_aggregate<<<(nDst + 3) / 4, 256, 0, stream>>>(x, srcIdx, rowStart, cnt, bufA, nDst);
}

extern "C" void kernel_launch(void* const* d_in, const int* in_sizes, int n_in,
                              void* d_out, int out_size, void* d_ws, size_t ws_size,
                              hipStream_t stream) {
    const float* x_paper   = (const float*)d_in[0];
    const float* x_author  = (const float*)d_in[1];
    const int*   ei_cites  = (const int*)d_in[2];
    const int*   ei_writes = (const int*)d_in[3];
    const int*   ei_written= (const int*)d_in[4];
    const float* W_cites   = (const float*)d_in[5];
    const float* b_cites   = (const float*)d_in[6];
    const float* W_writes  = (const float*)d_in[7];
    const float* b_writes  = (const float*)d_in[8];
    const float* W_written = (const float*)d_in[9];
    const float* b_written = (const float*)d_in[10];
    const float* Ws_paper  = (const float*)d_in[11];
    const float* bs_paper  = (const float*)d_in[12];
    const float* Ws_author = (const float*)d_in[13];
    const float* bs_author = (const float*)d_in[14];
    const float* Wc_paper  = (const float*)d_in[15];
    const float* bc_paper  = (const float*)d_in[16];
    const float* Wc_author = (const float*)d_in[17];
    const float* bc_author = (const float*)d_in[18];

    char* ws = (char*)d_ws;
    float* bufA = (float*)ws;
    int*   cntA = (int*)(ws + OFF_CNT);
    float* wsW  = (float*)(ws + OFF_W);
    float* wsB  = (float*)(ws + OFF_B);
    const float* ApT = wsW;
    const float* BpT = wsW + 16384;
    const float* CpT = wsW + 2*16384;
    const float* AaT = wsW + 3*16384;
    const float* BaT = wsW + 4*16384;
    const float* bp0 = wsB;
    const float* bpc = wsB + 128;
    const float* bpw = wsB + 2*128;
    const float* ba0 = wsB + 3*128;
    const float* bab = wsB + 4*128;

    float* out_p = (float*)d_out;
    float* out_a = out_p + (long long)NP*HID;

    fuse_w<<<640, 128, 0, stream>>>(Wc_paper, Ws_paper, W_cites, W_writes,
                                    Wc_author, Ws_author, W_written, wsW);
    fuse_b<<<3, 256, 0, stream>>>(Wc_paper, bs_paper, bc_paper, b_cites, b_writes,
                                  Wc_author, bs_author, bc_author, b_written, wsB);

    const int gP = (NP + 63) / 64;
    const int gA = (NA + 63) / 64;

    // ---- cites (paper -> paper) ----
    build_csr_and_aggregate(x_paper, ei_cites, NP, ws, stream);
    lin_pass<false,false,false,true,false><<<gP, 256, 0, stream>>>(
        x_paper, nullptr, ApT, bp0, out_p, NP);
    lin_pass<true,true,false,false,true><<<gP, 256, 0, stream>>>(
        bufA, cntA, BpT, bpc, out_p, NP);

    // ---- writes (author -> paper) ----
    build_csr_and_aggregate(x_author, ei_writes, NP, ws, stream);
    lin_pass<true,true,true,false,true><<<gP, 256, 0, stream>>>(
        bufA, cntA, CpT, bpw, out_p, NP);

    // ---- written (paper -> author) ----
    build_csr_and_aggregate(x_paper, ei_written, NA, ws, stream);
    lin_pass<false,false,false,true,false><<<gA, 256, 0, stream>>>(
        x_author, nullptr, AaT, ba0, out_a, NA);
    lin_pass<true,true,true,false,true><<<gA, 256, 0, stream>>>(
        bufA, cntA, BaT, bab, out_a, NA);
}

// Round 3
// 430.038 us; speedup vs baseline: 7.8870x; 2.5069x over previous
//
#include <hip/hip_runtime.h>

#define NP 100000
#define NA 50000
#define NE 500000
#define HID 128

typedef __attribute__((ext_vector_type(8))) short short8;
typedef __attribute__((ext_vector_type(4))) float floatx4;

// ---------------- workspace layout (bytes) ----------------
// mc (mean cites / ma): ushort[100000*128] @ 0          (25,600,000)
// mw (mean writes):     ushort[100000*128] @ 25,600,000 (25,600,000)
// cnt1: int[100000] @ 51,200,000
// cnt2: int[100000] @ 51,600,000
// rowStart @ 52,000,000 ; cursor @ 52,400,000 ; srcIdx @ 52,800,000 (2MB)
// bsum @ 54,800,000 (512)
// WcatP bf16[128][384] @ 54,800,512 (98,304)
// WcatA bf16[128][256] @ 54,898,816 (65,536)
// wsB fp32 5x128 @ 54,964,352 (2,560)
#define OFF_MC   0ull
#define OFF_MW   25600000ull
#define OFF_CNT1 51200000ull
#define OFF_CNT2 51600000ull
#define OFF_ROW  52000000ull
#define OFF_CUR  52400000ull
#define OFF_SRC  52800000ull
#define OFF_BSUM 54800000ull
#define OFF_WP   54800512ull
#define OFF_WA   54898816ull
#define OFF_B    54964352ull

__device__ __forceinline__ unsigned short f2bf(float f) {
    unsigned int u = __builtin_bit_cast(unsigned int, f);
    u += 0x7FFFu + ((u >> 16) & 1u);   // RNE (no NaN in this data)
    return (unsigned short)(u >> 16);
}

// ---------------- weight fusion (writes fused bf16 concat weights) ----------------
__global__ void fuse_w(const float* __restrict__ Wc_p, const float* __restrict__ Ws_p,
                       const float* __restrict__ W_cites, const float* __restrict__ W_writes,
                       const float* __restrict__ Wc_a, const float* __restrict__ Ws_a,
                       const float* __restrict__ W_written,
                       unsigned short* __restrict__ WcatP, unsigned short* __restrict__ WcatA) {
    int m = blockIdx.x >> 7;
    int r = blockIdx.x & 127;   // output row j
    int c = threadIdx.x;        // input col k
    const float* L; const float* R; float scale = 1.f;
    switch (m) {
        case 0:  L = Wc_p + r*256;       R = Ws_p;      break;            // Ap
        case 1:  L = Wc_p + r*256 + 128; R = W_cites;   scale = 0.5f; break; // Bp
        case 2:  L = Wc_p + r*256 + 128; R = W_writes;  scale = 0.5f; break; // Cp
        case 3:  L = Wc_a + r*256;       R = Ws_a;      break;            // Aa
        default: L = Wc_a + r*256 + 128; R = W_written; break;            // Ba
    }
    float acc = 0.f;
    for (int k = 0; k < 128; ++k) acc += L[k] * R[k*128 + c];
    unsigned short v = f2bf(scale * acc);
    if (m < 3) WcatP[r*384 + m*128 + c] = v;
    else       WcatA[r*256 + (m-3)*128 + c] = v;
}

__global__ void fuse_b(const float* __restrict__ Wc_p, const float* __restrict__ bs_p,
                       const float* __restrict__ bc_p, const float* __restrict__ b_cites,
                       const float* __restrict__ b_writes,
                       const float* __restrict__ Wc_a, const float* __restrict__ bs_a,
                       const float* __restrict__ bc_a, const float* __restrict__ b_written,
                       float* __restrict__ wsB) {
    int t = blockIdx.x * blockDim.x + threadIdx.x;
    if (t >= 640) return;
    int m = t >> 7, j = t & 127;
    float acc = 0.f;
    switch (m) {
        case 0:  for (int k = 0; k < 128; ++k) acc += Wc_p[j*256+k]     * bs_p[k];     acc += bc_p[j]; break;
        case 1:  for (int k = 0; k < 128; ++k) acc += Wc_p[j*256+128+k] * b_cites[k];  acc *= 0.5f;    break;
        case 2:  for (int k = 0; k < 128; ++k) acc += Wc_p[j*256+128+k] * b_writes[k]; acc *= 0.5f;    break;
        case 3:  for (int k = 0; k < 128; ++k) acc += Wc_a[j*256+k]     * bs_a[k];     acc += bc_a[j]; break;
        default: for (int k = 0; k < 128; ++k) acc += Wc_a[j*256+128+k] * b_written[k];                break;
    }
    wsB[m*128 + j] = acc;
}

// ---------------- CSR build ----------------
__global__ void hist_dst(const int* __restrict__ ei, int* __restrict__ cnt) {
    int e = blockIdx.x * blockDim.x + threadIdx.x;
    if (e < NE) atomicAdd(cnt + ei[NE + e], 1);
}

__global__ void scan_sums(const int* __restrict__ cnt, int* __restrict__ bsum, int n) {
    __shared__ int s[256];
    int base = blockIdx.x * 1024;
    int t = threadIdx.x;
    int v = 0;
#pragma unroll
    for (int j = 0; j < 4; ++j) { int i = base + t*4 + j; if (i < n) v += cnt[i]; }
    s[t] = v; __syncthreads();
    for (int off = 128; off > 0; off >>= 1) { if (t < off) s[t] += s[t+off]; __syncthreads(); }
    if (t == 0) bsum[blockIdx.x] = s[0];
}

__global__ void scan_tops(int* __restrict__ bsum, int nb) {
    __shared__ int s[128];
    int t = threadIdx.x;
    if (t < nb) s[t] = bsum[t];
    __syncthreads();
    if (t == 0) { int acc = 0; for (int i = 0; i < nb; ++i) { int v = s[i]; s[i] = acc; acc += v; } }
    __syncthreads();
    if (t < nb) bsum[t] = s[t];
}

__global__ void scan_chunks(const int* __restrict__ cnt, const int* __restrict__ bsum,
                            int* __restrict__ rowStart, int* __restrict__ cursor, int n) {
    __shared__ int s[256];
    int base = blockIdx.x * 1024;
    int t = threadIdx.x;
    int loc[4]; int v = 0;
#pragma unroll
    for (int j = 0; j < 4; ++j) { int i = base + t*4 + j; loc[j] = (i < n) ? cnt[i] : 0; v += loc[j]; }
    s[t] = v; __syncthreads();
    for (int off = 1; off < 256; off <<= 1) {
        int tmp = (t >= off) ? s[t - off] : 0;
        __syncthreads();
        s[t] += tmp;
        __syncthreads();
    }
    int excl = s[t] - v + bsum[blockIdx.x];
#pragma unroll
    for (int j = 0; j < 4; ++j) {
        int i = base + t*4 + j;
        if (i < n) { rowStart[i] = excl; cursor[i] = excl; excl += loc[j]; }
    }
}

__global__ void csr_fill(const int* __restrict__ ei, int* __restrict__ cursor,
                         int* __restrict__ srcIdx) {
    int e = blockIdx.x * blockDim.x + threadIdx.x;
    if (e < NE) {
        int d = ei[NE + e];
        int p = atomicAdd(cursor + d, 1);
        srcIdx[p] = ei[e];
    }
}

// ---------------- gather-aggregate -> bf16 MEAN (scale + convert fused) ----------------
__global__ __launch_bounds__(256) void csr_aggregate_mean(
        const float* __restrict__ x, const int* __restrict__ srcIdx,
        const int* __restrict__ rowStart, const int* __restrict__ cnt,
        unsigned short* __restrict__ mean, int nDst) {
    int wid = (int)((blockIdx.x * 256 + threadIdx.x) >> 6);
    int lane = threadIdx.x & 63;
    if (wid >= nDst) return;
    int beg = rowStart[wid];
    int n = cnt[wid];
    float2 a0 = make_float2(0.f, 0.f), a1 = make_float2(0.f, 0.f);
    int j = 0;
    for (; j + 2 <= n; j += 2) {
        int s0 = srcIdx[beg + j];
        int s1 = srcIdx[beg + j + 1];
        float2 v0 = ((const float2*)x)[(long long)s0 * 64 + lane];
        float2 v1 = ((const float2*)x)[(long long)s1 * 64 + lane];
        a0.x += v0.x; a0.y += v0.y;
        a1.x += v1.x; a1.y += v1.y;
    }
    if (j < n) {
        int s0 = srcIdx[beg + j];
        float2 v0 = ((const float2*)x)[(long long)s0 * 64 + lane];
        a0.x += v0.x; a0.y += v0.y;
    }
    float sc = 1.f / (float)max(n, 1);
    float mx = (a0.x + a1.x) * sc;
    float my = (a0.y + a1.y) * sc;
    unsigned int packed = (unsigned int)f2bf(mx) | ((unsigned int)f2bf(my) << 16);
    ((unsigned int*)mean)[(long long)wid * 64 + lane] = packed;
}

// ---------------- MFMA GEMM: out = relu(concat(x, m1[, m2]) @ Wcat^T + gated biases) ----
// block 256 thr = 4 waves (2M x 2N); wave: 32 rows x 64 cols; frag 16x16x32 bf16.
// A layout: lane holds row (l&15), k = (l>>4)*8..+7 ; B: col (l&15), same k.
// C/D: col = l&15, row = (l>>4)*4 + reg.
template<int NSEG>
__global__ __launch_bounds__(256) void mfma_gemm(
        const float* __restrict__ x,
        const unsigned short* __restrict__ m1,
        const unsigned short* __restrict__ m2,
        const int* __restrict__ cnt1,
        const int* __restrict__ cnt2,
        const unsigned short* __restrict__ Wcat,
        const float* __restrict__ b0,
        const float* __restrict__ b1,
        const float* __restrict__ b2,
        float* __restrict__ out, int nRows) {
    constexpr int K = NSEG * 128;
    int tid = threadIdx.x;
    int lane = tid & 63;
    int wid = tid >> 6;
    int wm = wid >> 1, wn = wid & 1;
    int row0 = blockIdx.x * 64 + wm * 32;
    int colBase = wn * 64;
    int l15 = lane & 15;
    int kg = lane >> 4;

    int rA0 = min(row0 + l15,      nRows - 1);
    int rA1 = min(row0 + 16 + l15, nRows - 1);

    floatx4 acc[2][4] = {};

    for (int s = 0; s < NSEG * 4; ++s) {
        int kk = (s & 3) * 32 + kg * 8;     // k within segment
        short8 a0, a1;
        if (s < 4) {
            const float* p0 = x + (long long)rA0 * 128 + kk;
            const float* p1 = x + (long long)rA1 * 128 + kk;
            floatx4 u0 = *(const floatx4*)p0;
            floatx4 u1 = *(const floatx4*)(p0 + 4);
            floatx4 v0 = *(const floatx4*)p1;
            floatx4 v1 = *(const floatx4*)(p1 + 4);
#pragma unroll
            for (int j = 0; j < 4; ++j) {
                a0[j]     = (short)f2bf(u0[j]);
                a0[j + 4] = (short)f2bf(u1[j]);
                a1[j]     = (short)f2bf(v0[j]);
                a1[j + 4] = (short)f2bf(v1[j]);
            }
        } else {
            const unsigned short* src = (NSEG == 3 && s >= 8) ? m2 : m1;
            a0 = *(const short8*)(src + (long long)rA0 * 128 + kk);
            a1 = *(const short8*)(src + (long long)rA1 * 128 + kk);
        }
        int kcat = s * 32 + kg * 8;
        const unsigned short* wp = Wcat + (long long)(colBase + l15) * K + kcat;
        short8 bf0 = *(const short8*)(wp);
        short8 bf1 = *(const short8*)(wp + 16 * K);
        short8 bf2 = *(const short8*)(wp + 32 * K);
        short8 bf3 = *(const short8*)(wp + 48 * K);

        acc[0][0] = __builtin_amdgcn_mfma_f32_16x16x32_bf16(a0, bf0, acc[0][0], 0, 0, 0);
        acc[0][1] = __builtin_amdgcn_mfma_f32_16x16x32_bf16(a0, bf1, acc[0][1], 0, 0, 0);
        acc[0][2] = __builtin_amdgcn_mfma_f32_16x16x32_bf16(a0, bf2, acc[0][2], 0, 0, 0);
        acc[0][3] = __builtin_amdgcn_mfma_f32_16x16x32_bf16(a0, bf3, acc[0][3], 0, 0, 0);
        acc[1][0] = __builtin_amdgcn_mfma_f32_16x16x32_bf16(a1, bf0, acc[1][0], 0, 0, 0);
        acc[1][1] = __builtin_amdgcn_mfma_f32_16x16x32_bf16(a1, bf1, acc[1][1], 0, 0, 0);
        acc[1][2] = __builtin_amdgcn_mfma_f32_16x16x32_bf16(a1, bf2, acc[1][2], 0, 0, 0);
        acc[1][3] = __builtin_amdgcn_mfma_f32_16x16x32_bf16(a1, bf3, acc[1][3], 0, 0, 0);
    }

    float bb0[4], bb1[4], bb2[4];
#pragma unroll
    for (int n = 0; n < 4; ++n) {
        int col = colBase + n * 16 + l15;
        bb0[n] = b0[col];
        bb1[n] = b1[col];
        bb2[n] = (NSEG == 3) ? b2[col] : 0.f;
    }
    int rb = kg * 4;
#pragma unroll
    for (int m = 0; m < 2; ++m) {
#pragma unroll
        for (int r = 0; r < 4; ++r) {
            int gr = row0 + m * 16 + rb + r;
            if (gr >= nRows) continue;
            float mk1 = (cnt1[gr] > 0) ? 1.f : 0.f;
            float mk2 = (NSEG == 3) ? ((cnt2[gr] > 0) ? 1.f : 0.f) : 0.f;
            float* op = out + (long long)gr * 128 + colBase + l15;
#pragma unroll
            for (int n = 0; n < 4; ++n) {
                float v = acc[m][n][r] + bb0[n] + mk1 * bb1[n] + mk2 * bb2[n];
                op[n * 16] = fmaxf(v, 0.f);
            }
        }
    }
}

static inline void build_csr_and_mean(const float* x, const int* ei, int nDst,
                                      int* cnt, unsigned short* mean,
                                      char* ws, hipStream_t stream) {
    int* rowStart = (int*)(ws + OFF_ROW);
    int* cursor   = (int*)(ws + OFF_CUR);
    int* srcIdx   = (int*)(ws + OFF_SRC);
    int* bsum     = (int*)(ws + OFF_BSUM);

    const int edgeBlocks = (NE + 255) / 256;
    const int nChunks = (nDst + 1023) / 1024;

    hipMemsetAsync(cnt, 0, (size_t)nDst * 4, stream);
    hist_dst<<<edgeBlocks, 256, 0, stream>>>(ei, cnt);
    scan_sums<<<nChunks, 256, 0, stream>>>(cnt, bsum, nDst);
    scan_tops<<<1, 128, 0, stream>>>(bsum, nChunks);
    scan_chunks<<<nChunks, 256, 0, stream>>>(cnt, bsum, rowStart, cursor, nDst);
    csr_fill<<<edgeBlocks, 256, 0, stream>>>(ei, cursor, srcIdx);
    csr_aggregate_mean<<<(nDst + 3) / 4, 256, 0, stream>>>(x, srcIdx, rowStart, cnt, mean, nDst);
}

extern "C" void kernel_launch(void* const* d_in, const int* in_sizes, int n_in,
                              void* d_out, int out_size, void* d_ws, size_t ws_size,
                              hipStream_t stream) {
    const float* x_paper   = (const float*)d_in[0];
    const float* x_author  = (const float*)d_in[1];
    const int*   ei_cites  = (const int*)d_in[2];
    const int*   ei_writes = (const int*)d_in[3];
    const int*   ei_written= (const int*)d_in[4];
    const float* W_cites   = (const float*)d_in[5];
    const float* b_cites   = (const float*)d_in[6];
    const float* W_writes  = (const float*)d_in[7];
    const float* b_writes  = (const float*)d_in[8];
    const float* W_written = (const float*)d_in[9];
    const float* b_written = (const float*)d_in[10];
    const float* Ws_paper  = (const float*)d_in[11];
    const float* bs_paper  = (const float*)d_in[12];
    const float* Ws_author = (const float*)d_in[13];
    const float* bs_author = (const float*)d_in[14];
    const float* Wc_paper  = (const float*)d_in[15];
    const float* bc_paper  = (const float*)d_in[16];
    const float* Wc_author = (const float*)d_in[17];
    const float* bc_author = (const float*)d_in[18];

    char* ws = (char*)d_ws;
    unsigned short* mc = (unsigned short*)(ws + OFF_MC);
    unsigned short* mw = (unsigned short*)(ws + OFF_MW);
    int* cnt1 = (int*)(ws + OFF_CNT1);
    int* cnt2 = (int*)(ws + OFF_CNT2);
    unsigned short* WcatP = (unsigned short*)(ws + OFF_WP);
    unsigned short* WcatA = (unsigned short*)(ws + OFF_WA);
    float* wsB = (float*)(ws + OFF_B);
    const float* bp0 = wsB;
    const float* bpc = wsB + 128;
    const float* bpw = wsB + 2*128;
    const float* ba0 = wsB + 3*128;
    const float* bab = wsB + 4*128;

    float* out_p = (float*)d_out;
    float* out_a = out_p + (long long)NP*HID;

    fuse_w<<<640, 128, 0, stream>>>(Wc_paper, Ws_paper, W_cites, W_writes,
                                    Wc_author, Ws_author, W_written, WcatP, WcatA);
    fuse_b<<<3, 256, 0, stream>>>(Wc_paper, bs_paper, bc_paper, b_cites, b_writes,
                                  Wc_author, bs_author, bc_author, b_written, wsB);

    // cites: paper -> paper (mean into mc, counts into cnt1)
    build_csr_and_mean(x_paper, ei_cites, NP, cnt1, mc, ws, stream);
    // writes: author -> paper (mean into mw, counts into cnt2)
    build_csr_and_mean(x_author, ei_writes, NP, cnt2, mw, ws, stream);

    // paper output GEMM
    mfma_gemm<3><<<(NP + 63) / 64, 256, 0, stream>>>(
        x_paper, mc, mw, cnt1, cnt2, WcatP, bp0, bpc, bpw, out_p, NP);

    // written: paper -> author (mean reuses mc space, counts reuse cnt1)
    build_csr_and_mean(x_paper, ei_written, NA, cnt1, mc, ws, stream);

    // author output GEMM
    mfma_gemm<2><<<(NA + 63) / 64, 256, 0, stream>>>(
        x_author, mc, nullptr, cnt1, nullptr, WcatA, ba0, bab, nullptr, out_a, NA);
}

// Round 4
// 423.144 us; speedup vs baseline: 8.0155x; 1.0163x over previous
//
#include <hip/hip_runtime.h>

#define NP 100000
#define NA 50000
#define NE 500000
#define HID 128

typedef __attribute__((ext_vector_type(8))) short short8;
typedef __attribute__((ext_vector_type(4))) float floatx4;

// ---------------- workspace layout (bytes) ----------------
// mc: ushort[100000*128] @ 0          (25,600,000)   mean cites / mean written (reused)
// mw: ushort[100000*128] @ 25,600,000 (25,600,000)   mean writes
// cnt1 @ 51,200,000 ; cnt2 @ 51,600,000
// rowStart @ 52,000,000 ; cursor @ 52,400,000 ; srcIdx @ 52,800,000 (2MB)
// bsum @ 54,800,000 ; WcatP @ 54,800,512 ; WcatA @ 54,898,816 ; wsB @ 54,964,352
// xbf_p (bf16 x_paper) lives in the out_a region of d_out (dead until author GEMM).
#define OFF_MC   0ull
#define OFF_MW   25600000ull
#define OFF_CNT1 51200000ull
#define OFF_CNT2 51600000ull
#define OFF_ROW  52000000ull
#define OFF_CUR  52400000ull
#define OFF_SRC  52800000ull
#define OFF_BSUM 54800000ull
#define OFF_WP   54800512ull
#define OFF_WA   54898816ull
#define OFF_B    54964352ull

__device__ __forceinline__ unsigned short f2bf(float f) {
    unsigned int u = __builtin_bit_cast(unsigned int, f);
    u += 0x7FFFu + ((u >> 16) & 1u);   // RNE
    return (unsigned short)(u >> 16);
}
__device__ __forceinline__ unsigned int pack2(float a, float b) {
    return (unsigned int)f2bf(a) | ((unsigned int)f2bf(b) << 16);
}
__device__ __forceinline__ float bflo(unsigned int u) {
    return __builtin_bit_cast(float, u << 16);
}
__device__ __forceinline__ float bfhi(unsigned int u) {
    return __builtin_bit_cast(float, u & 0xFFFF0000u);
}

// ---------------- x fp32 -> bf16 (16B/lane) ----------------
__global__ __launch_bounds__(256) void to_bf16(const float* __restrict__ x,
                                               uint4* __restrict__ xb, int n8) {
    int i = blockIdx.x * blockDim.x + threadIdx.x;
    if (i >= n8) return;
    floatx4 u0 = ((const floatx4*)x)[(long long)i*2];
    floatx4 u1 = ((const floatx4*)x)[(long long)i*2 + 1];
    uint4 o;
    o.x = pack2(u0[0], u0[1]); o.y = pack2(u0[2], u0[3]);
    o.z = pack2(u1[0], u1[1]); o.w = pack2(u1[2], u1[3]);
    xb[i] = o;
}

// ---------------- weight fusion ----------------
__global__ void fuse_w(const float* __restrict__ Wc_p, const float* __restrict__ Ws_p,
                       const float* __restrict__ W_cites, const float* __restrict__ W_writes,
                       const float* __restrict__ Wc_a, const float* __restrict__ Ws_a,
                       const float* __restrict__ W_written,
                       unsigned short* __restrict__ WcatP, unsigned short* __restrict__ WcatA) {
    int m = blockIdx.x >> 7;
    int r = blockIdx.x & 127;
    int c = threadIdx.x;
    const float* L; const float* R; float scale = 1.f;
    switch (m) {
        case 0:  L = Wc_p + r*256;       R = Ws_p;      break;
        case 1:  L = Wc_p + r*256 + 128; R = W_cites;   scale = 0.5f; break;
        case 2:  L = Wc_p + r*256 + 128; R = W_writes;  scale = 0.5f; break;
        case 3:  L = Wc_a + r*256;       R = Ws_a;      break;
        default: L = Wc_a + r*256 + 128; R = W_written; break;
    }
    float acc = 0.f;
    for (int k = 0; k < 128; ++k) acc += L[k] * R[k*128 + c];
    unsigned short v = f2bf(scale * acc);
    if (m < 3) WcatP[r*384 + m*128 + c] = v;
    else       WcatA[r*256 + (m-3)*128 + c] = v;
}

__global__ void fuse_b(const float* __restrict__ Wc_p, const float* __restrict__ bs_p,
                       const float* __restrict__ bc_p, const float* __restrict__ b_cites,
                       const float* __restrict__ b_writes,
                       const float* __restrict__ Wc_a, const float* __restrict__ bs_a,
                       const float* __restrict__ bc_a, const float* __restrict__ b_written,
                       float* __restrict__ wsB) {
    int t = blockIdx.x * blockDim.x + threadIdx.x;
    if (t >= 640) return;
    int m = t >> 7, j = t & 127;
    float acc = 0.f;
    switch (m) {
        case 0:  for (int k = 0; k < 128; ++k) acc += Wc_p[j*256+k]     * bs_p[k];     acc += bc_p[j]; break;
        case 1:  for (int k = 0; k < 128; ++k) acc += Wc_p[j*256+128+k] * b_cites[k];  acc *= 0.5f;    break;
        case 2:  for (int k = 0; k < 128; ++k) acc += Wc_p[j*256+128+k] * b_writes[k]; acc *= 0.5f;    break;
        case 3:  for (int k = 0; k < 128; ++k) acc += Wc_a[j*256+k]     * bs_a[k];     acc += bc_a[j]; break;
        default: for (int k = 0; k < 128; ++k) acc += Wc_a[j*256+128+k] * b_written[k];                break;
    }
    wsB[m*128 + j] = acc;
}

// ---------------- CSR build ----------------
__global__ void hist_dst(const int* __restrict__ ei, int* __restrict__ cnt) {
    int e = blockIdx.x * blockDim.x + threadIdx.x;
    if (e < NE) atomicAdd(cnt + ei[NE + e], 1);
}

__global__ void scan_sums(const int* __restrict__ cnt, int* __restrict__ bsum, int n) {
    __shared__ int s[256];
    int base = blockIdx.x * 1024;
    int t = threadIdx.x;
    int v = 0;
#pragma unroll
    for (int j = 0; j < 4; ++j) { int i = base + t*4 + j; if (i < n) v += cnt[i]; }
    s[t] = v; __syncthreads();
    for (int off = 128; off > 0; off >>= 1) { if (t < off) s[t] += s[t+off]; __syncthreads(); }
    if (t == 0) bsum[blockIdx.x] = s[0];
}

__global__ void scan_tops(int* __restrict__ bsum, int nb) {
    __shared__ int s[128];
    int t = threadIdx.x;
    if (t < nb) s[t] = bsum[t];
    __syncthreads();
    if (t == 0) { int acc = 0; for (int i = 0; i < nb; ++i) { int v = s[i]; s[i] = acc; acc += v; } }
    __syncthreads();
    if (t < nb) bsum[t] = s[t];
}

__global__ void scan_chunks(const int* __restrict__ cnt, const int* __restrict__ bsum,
                            int* __restrict__ rowStart, int* __restrict__ cursor, int n) {
    __shared__ int s[256];
    int base = blockIdx.x * 1024;
    int t = threadIdx.x;
    int loc[4]; int v = 0;
#pragma unroll
    for (int j = 0; j < 4; ++j) { int i = base + t*4 + j; loc[j] = (i < n) ? cnt[i] : 0; v += loc[j]; }
    s[t] = v; __syncthreads();
    for (int off = 1; off < 256; off <<= 1) {
        int tmp = (t >= off) ? s[t - off] : 0;
        __syncthreads();
        s[t] += tmp;
        __syncthreads();
    }
    int excl = s[t] - v + bsum[blockIdx.x];
#pragma unroll
    for (int j = 0; j < 4; ++j) {
        int i = base + t*4 + j;
        if (i < n) { rowStart[i] = excl; cursor[i] = excl; excl += loc[j]; }
    }
}

__global__ void csr_fill(const int* __restrict__ ei, int* __restrict__ cursor,
                         int* __restrict__ srcIdx) {
    int e = blockIdx.x * blockDim.x + threadIdx.x;
    if (e < NE) {
        int d = ei[NE + e];
        int p = atomicAdd(cursor + d, 1);
        srcIdx[p] = ei[e];
    }
}

// ---------------- gather-aggregate -> bf16 mean; BF: source already bf16 ----------------
template<bool BF>
__global__ __launch_bounds__(256) void csr_aggregate_mean(
        const void* __restrict__ xsrc, const int* __restrict__ srcIdx,
        const int* __restrict__ rowStart, const int* __restrict__ cnt,
        unsigned int* __restrict__ mean, int nDst) {
    int wid = (int)((blockIdx.x * 256 + threadIdx.x) >> 6);
    int lane = threadIdx.x & 63;
    if (wid >= nDst) return;
    int beg = rowStart[wid];
    int n = cnt[wid];
    float ax0 = 0.f, ay0 = 0.f, ax1 = 0.f, ay1 = 0.f;
    int j = 0;
    for (; j + 2 <= n; j += 2) {
        int s0 = srcIdx[beg + j];
        int s1 = srcIdx[beg + j + 1];
        if (BF) {
            unsigned int u0 = ((const unsigned int*)xsrc)[(long long)s0 * 64 + lane];
            unsigned int u1 = ((const unsigned int*)xsrc)[(long long)s1 * 64 + lane];
            ax0 += bflo(u0); ay0 += bfhi(u0);
            ax1 += bflo(u1); ay1 += bfhi(u1);
        } else {
            float2 v0 = ((const float2*)xsrc)[(long long)s0 * 64 + lane];
            float2 v1 = ((const float2*)xsrc)[(long long)s1 * 64 + lane];
            ax0 += v0.x; ay0 += v0.y;
            ax1 += v1.x; ay1 += v1.y;
        }
    }
    if (j < n) {
        int s0 = srcIdx[beg + j];
        if (BF) {
            unsigned int u0 = ((const unsigned int*)xsrc)[(long long)s0 * 64 + lane];
            ax0 += bflo(u0); ay0 += bfhi(u0);
        } else {
            float2 v0 = ((const float2*)xsrc)[(long long)s0 * 64 + lane];
            ax0 += v0.x; ay0 += v0.y;
        }
    }
    float sc = 1.f / (float)max(n, 1);
    mean[(long long)wid * 64 + lane] = pack2((ax0 + ax1) * sc, (ay0 + ay1) * sc);
}

// ---------------- MFMA GEMM ----------------
// block 256 thr = 4 waves (2M x 2N); wave: 32 rows x 64 cols; 16x16x32 bf16 frags.
// AXBF: segment-0 A source is pre-converted bf16 (xbf); else fp32 x with inline convert.
template<int NSEG, bool AXBF>
__global__ __launch_bounds__(256) void mfma_gemm(
        const float* __restrict__ x,
        const unsigned short* __restrict__ xbf,
        const unsigned short* __restrict__ m1,
        const unsigned short* __restrict__ m2,
        const int* __restrict__ cnt1,
        const int* __restrict__ cnt2,
        const unsigned short* __restrict__ Wcat,
        const float* __restrict__ b0,
        const float* __restrict__ b1,
        const float* __restrict__ b2,
        float* __restrict__ out, int nRows) {
    constexpr int K = NSEG * 128;
    int tid = threadIdx.x;
    int lane = tid & 63;
    int wid = tid >> 6;
    int wm = wid >> 1, wn = wid & 1;
    int row0 = blockIdx.x * 64 + wm * 32;
    int colBase = wn * 64;
    int l15 = lane & 15;
    int kg = lane >> 4;

    int rA0 = min(row0 + l15,      nRows - 1);
    int rA1 = min(row0 + 16 + l15, nRows - 1);

    floatx4 acc[2][4] = {};

#pragma unroll
    for (int s = 0; s < NSEG * 4; ++s) {
        int kk = (s & 3) * 32 + kg * 8;
        short8 a0, a1;
        if (s < 4 && !AXBF) {
            const float* p0 = x + (long long)rA0 * 128 + kk;
            const float* p1 = x + (long long)rA1 * 128 + kk;
            floatx4 u0 = *(const floatx4*)p0;
            floatx4 u1 = *(const floatx4*)(p0 + 4);
            floatx4 v0 = *(const floatx4*)p1;
            floatx4 v1 = *(const floatx4*)(p1 + 4);
#pragma unroll
            for (int j = 0; j < 4; ++j) {
                a0[j]     = (short)f2bf(u0[j]);
                a0[j + 4] = (short)f2bf(u1[j]);
                a1[j]     = (short)f2bf(v0[j]);
                a1[j + 4] = (short)f2bf(v1[j]);
            }
        } else {
            const unsigned short* src =
                (s < 4) ? xbf : ((NSEG == 3 && s >= 8) ? m2 : m1);
            a0 = *(const short8*)(src + (long long)rA0 * 128 + kk);
            a1 = *(const short8*)(src + (long long)rA1 * 128 + kk);
        }
        int kcat = s * 32 + kg * 8;
        const unsigned short* wp = Wcat + (long long)(colBase + l15) * K + kcat;
        short8 bf0 = *(const short8*)(wp);
        short8 bf1 = *(const short8*)(wp + 16 * K);
        short8 bf2 = *(const short8*)(wp + 32 * K);
        short8 bf3 = *(const short8*)(wp + 48 * K);

        acc[0][0] = __builtin_amdgcn_mfma_f32_16x16x32_bf16(a0, bf0, acc[0][0], 0, 0, 0);
        acc[0][1] = __builtin_amdgcn_mfma_f32_16x16x32_bf16(a0, bf1, acc[0][1], 0, 0, 0);
        acc[0][2] = __builtin_amdgcn_mfma_f32_16x16x32_bf16(a0, bf2, acc[0][2], 0, 0, 0);
        acc[0][3] = __builtin_amdgcn_mfma_f32_16x16x32_bf16(a0, bf3, acc[0][3], 0, 0, 0);
        acc[1][0] = __builtin_amdgcn_mfma_f32_16x16x32_bf16(a1, bf0, acc[1][0], 0, 0, 0);
        acc[1][1] = __builtin_amdgcn_mfma_f32_16x16x32_bf16(a1, bf1, acc[1][1], 0, 0, 0);
        acc[1][2] = __builtin_amdgcn_mfma_f32_16x16x32_bf16(a1, bf2, acc[1][2], 0, 0, 0);
        acc[1][3] = __builtin_amdgcn_mfma_f32_16x16x32_bf16(a1, bf3, acc[1][3], 0, 0, 0);
    }

    float bb0[4], bb1[4], bb2[4];
#pragma unroll
    for (int n = 0; n < 4; ++n) {
        int col = colBase + n * 16 + l15;
        bb0[n] = b0[col];
        bb1[n] = b1[col];
        bb2[n] = (NSEG == 3) ? b2[col] : 0.f;
    }
    int rb = kg * 4;
#pragma unroll
    for (int m = 0; m < 2; ++m) {
#pragma unroll
        for (int r = 0; r < 4; ++r) {
            int gr = row0 + m * 16 + rb + r;
            if (gr >= nRows) continue;
            float mk1 = (cnt1[gr] > 0) ? 1.f : 0.f;
            float mk2 = (NSEG == 3) ? ((cnt2[gr] > 0) ? 1.f : 0.f) : 0.f;
            float* op = out + (long long)gr * 128 + colBase + l15;
#pragma unroll
            for (int n = 0; n < 4; ++n) {
                float v = acc[m][n][r] + bb0[n] + mk1 * bb1[n] + mk2 * bb2[n];
                op[n * 16] = fmaxf(v, 0.f);
            }
        }
    }
}

static inline void build_csr(const int* ei, int nDst, char* ws, hipStream_t stream) {
    int* cnt      = (int*)(ws + OFF_CNT1);   // overwritten per-chain caller picks
    (void)cnt;
}

static inline void run_chain(const void* xsrc, bool srcBF, const int* ei, int nDst,
                             int* cnt, unsigned int* mean, char* ws, hipStream_t stream) {
    int* rowStart = (int*)(ws + OFF_ROW);
    int* cursor   = (int*)(ws + OFF_CUR);
    int* srcIdx   = (int*)(ws + OFF_SRC);
    int* bsum     = (int*)(ws + OFF_BSUM);

    const int edgeBlocks = (NE + 255) / 256;
    const int nChunks = (nDst + 1023) / 1024;

    hipMemsetAsync(cnt, 0, (size_t)nDst * 4, stream);
    hist_dst<<<edgeBlocks, 256, 0, stream>>>(ei, cnt);
    scan_sums<<<nChunks, 256, 0, stream>>>(cnt, bsum, nDst);
    scan_tops<<<1, 128, 0, stream>>>(bsum, nChunks);
    scan_chunks<<<nChunks, 256, 0, stream>>>(cnt, bsum, rowStart, cursor, nDst);
    csr_fill<<<edgeBlocks, 256, 0, stream>>>(ei, cursor, srcIdx);
    if (srcBF)
        csr_aggregate_mean<true><<<(nDst + 3) / 4, 256, 0, stream>>>(
            xsrc, srcIdx, rowStart, cnt, mean, nDst);
    else
        csr_aggregate_mean<false><<<(nDst + 3) / 4, 256, 0, stream>>>(
            xsrc, srcIdx, rowStart, cnt, mean, nDst);
}

extern "C" void kernel_launch(void* const* d_in, const int* in_sizes, int n_in,
                              void* d_out, int out_size, void* d_ws, size_t ws_size,
                              hipStream_t stream) {
    const float* x_paper   = (const float*)d_in[0];
    const float* x_author  = (const float*)d_in[1];
    const int*   ei_cites  = (const int*)d_in[2];
    const int*   ei_writes = (const int*)d_in[3];
    const int*   ei_written= (const int*)d_in[4];
    const float* W_cites   = (const float*)d_in[5];
    const float* b_cites   = (const float*)d_in[6];
    const float* W_writes  = (const float*)d_in[7];
    const float* b_writes  = (const float*)d_in[8];
    const float* W_written = (const float*)d_in[9];
    const float* b_written = (const float*)d_in[10];
    const float* Ws_paper  = (const float*)d_in[11];
    const float* bs_paper  = (const float*)d_in[12];
    const float* Ws_author = (const float*)d_in[13];
    const float* bs_author = (const float*)d_in[14];
    const float* Wc_paper  = (const float*)d_in[15];
    const float* bc_paper  = (const float*)d_in[16];
    const float* Wc_author = (const float*)d_in[17];
    const float* bc_author = (const float*)d_in[18];

    char* ws = (char*)d_ws;
    unsigned int* mc = (unsigned int*)(ws + OFF_MC);
    unsigned int* mw = (unsigned int*)(ws + OFF_MW);
    int* cnt1 = (int*)(ws + OFF_CNT1);
    int* cnt2 = (int*)(ws + OFF_CNT2);
    unsigned short* WcatP = (unsigned short*)(ws + OFF_WP);
    unsigned short* WcatA = (unsigned short*)(ws + OFF_WA);
    float* wsB = (float*)(ws + OFF_B);
    const float* bp0 = wsB;
    const float* bpc = wsB + 128;
    const float* bpw = wsB + 2*128;
    const float* ba0 = wsB + 3*128;
    const float* bab = wsB + 4*128;

    float* out_p = (float*)d_out;
    float* out_a = out_p + (long long)NP*HID;
    // x_paper bf16 stash in the (currently dead) out_a region: 100000*128*2 B = 25.6 MB
    unsigned short* xbf_p = (unsigned short*)out_a;

    to_bf16<<<(NP*HID/8 + 255) / 256, 256, 0, stream>>>(x_paper, (uint4*)xbf_p, NP*HID/8);
    fuse_w<<<640, 128, 0, stream>>>(Wc_paper, Ws_paper, W_cites, W_writes,
                                    Wc_author, Ws_author, W_written, WcatP, WcatA);
    fuse_b<<<3, 256, 0, stream>>>(Wc_paper, bs_paper, bc_paper, b_cites, b_writes,
                                  Wc_author, bs_author, bc_author, b_written, wsB);

    // cites: paper -> paper (bf16 gather)
    run_chain(xbf_p, true, ei_cites, NP, cnt1, mc, ws, stream);
    // writes: author -> paper (fp32 gather)
    run_chain(x_author, false, ei_writes, NP, cnt2, mw, ws, stream);

    // paper output GEMM (A seg0 = bf16 xbf_p)
    mfma_gemm<3, true><<<(NP + 63) / 64, 256, 0, stream>>>(
        nullptr, xbf_p, (const unsigned short*)mc, (const unsigned short*)mw,
        cnt1, cnt2, WcatP, bp0, bpc, bpw, out_p, NP);

    // written: paper -> author (bf16 gather; mean reuses mc, counts reuse cnt1)
    run_chain(xbf_p, true, ei_written, NA, cnt1, mc, ws, stream);

    // author output GEMM (A seg0 = fp32 x_author, inline convert) — overwrites xbf_p region
    mfma_gemm<2, false><<<(NA + 63) / 64, 256, 0, stream>>>(
        x_author, nullptr, (const unsigned short*)mc, nullptr,
        cnt1, nullptr, WcatA, ba0, bab, nullptr, out_a, NA);
}